// Round 8
// baseline (338.527 us; speedup 1.0000x reference)
//
#include <hip/hip_runtime.h>

#define HIDDEN        128
#define TPB           1024
#define PPT           16                   // paths per thread
#define CHUNK_NODES   25600                // nodes per LDS chunk
#define PLANE_STRIDE  26112                // u16 per plane (chunk bytes % 1024 == 0)
#define CHUNK_U16     (3 * PLANE_STRIDE)   // 78336
#define CHUNK_BYTES   (CHUNK_U16 * 2)      // 156672 (152.9 KB LDS)
#define FILL_UNITS    (CHUNK_BYTES / 1024) // 153 x 1KB wave DMA units
#define PAD_BYTE      (CHUNK_NODES * 2)    // 51200: clamp target inside plane

typedef int   v4i __attribute__((ext_vector_type(4)));
typedef float v4f __attribute__((ext_vector_type(4)));
typedef unsigned short u16;
typedef unsigned int   u32;

static __device__ __forceinline__ u16 f32_to_f16_bits(float x) {
    union { _Float16 h; u16 u; } cv;
    cv.h = (_Float16)x;
    return cv.u;
}

// Async global->LDS DMA, 16 B per lane: lane i's 16 B land at lds_base + i*16.
static __device__ __forceinline__ void gload_lds16(const void* gp, void* lp) {
    __builtin_amdgcn_global_load_lds(
        (const __attribute__((address_space(1))) unsigned int*)gp,
        (__attribute__((address_space(3))) unsigned int*)lp,
        16, 0, 0);
}

// Kernel 1: f16 table, chunked layout. Chunk c = 3 planes of PLANE_STRIDE u16;
// plane-local index 25600 (PAD_BYTE/2) is the zero slot that invalid /
// out-of-chunk gathers clamp onto. One wave per node.
__global__ __launch_bounds__(256) void proj_kernel(
    const float* __restrict__ feat,   // (n_nodes, 128)
    const float* __restrict__ W,      // (3, 1, 128)
    u16* __restrict__ proj_h,         // nchunks * CHUNK_U16
    int n_nodes, int nchunks)
{
    int gtid = blockIdx.x * blockDim.x + threadIdx.x;

    // Zero the clamp slots: one per (chunk, plane).
    if (gtid < nchunks * 3) {
        int c = gtid / 3, l = gtid - 3 * c;
        proj_h[(size_t)c * CHUNK_U16 + l * PLANE_STRIDE + CHUNK_NODES] = 0;
    }

    int node = gtid >> 6;
    int lane = threadIdx.x & 63;
    if (node >= n_nodes) return;

    const float2* f2 = (const float2*)(feat + (size_t)node * HIDDEN);
    const float2* w2 = (const float2*)W;

    float2 f   = f2[lane];
    float2 w0  = w2[lane];           // W[0]
    float2 w1  = w2[64 + lane];      // W[1]
    float2 wv2 = w2[128 + lane];     // W[2]

    float s0 = f.x * w0.x  + f.y * w0.y;
    float s1 = f.x * w1.x  + f.y * w1.y;
    float s2 = f.x * wv2.x + f.y * wv2.y;

    #pragma unroll
    for (int off = 32; off > 0; off >>= 1) {
        s0 += __shfl_xor(s0, off, 64);
        s1 += __shfl_xor(s1, off, 64);
        s2 += __shfl_xor(s2, off, 64);
    }

    if (lane == 0) {
        int c     = node / CHUNK_NODES;
        int local = node - c * CHUNK_NODES;
        u16* base = proj_h + (size_t)c * CHUNK_U16 + local;
        base[0]                = f32_to_f16_bits(s0);
        base[PLANE_STRIDE]     = f32_to_f16_bits(s1);
        base[2 * PLANE_STRIDE] = f32_to_f16_bits(s2);
    }
}

// Kernel 2: 16 paths/thread in registers (pre-doubled byte ids); 4 chunk
// passes. Fill = async global_load_lds (zero per-iteration waits; the
// __syncthreads is the drain). Gather addressing is 2 VALU ops:
//   off = min((u32)(id2 - cbase2), PAD_BYTE)   -> clamp lands on zero slot.
// Grid padded to 3 blocks/CU exactly; overrun threads clamp loads, skip
// stores, and run every barrier.
__global__ __launch_bounds__(TPB, 4) void score_kernel(
    const int* __restrict__ paths,    // (n_paths, 3) int32
    const u16* __restrict__ proj_h,   // chunked f16 table
    float* __restrict__ out,          // (n_paths,)
    int n_threads, int nchunks)
{
    extern __shared__ u16 lds[];
    const char* ldsb = (const char*)lds;

    int t    = blockIdx.x * TPB + threadIdx.x;
    int tl   = t < n_threads ? t : n_threads - 1;   // clamp: uniform flow
    int wid  = threadIdx.x >> 6;
    int lane = threadIdx.x & 63;

    // 16 paths = 48 ids = 12 int4 loads; store ids pre-doubled (byte units;
    // sign preserved for the validity count at the end).
    int ids2[3 * PPT];
    const v4i* p4 = (const v4i*)paths;
    #pragma unroll
    for (int i = 0; i < 12; ++i) {
        v4i v = __builtin_nontemporal_load(p4 + (size_t)tl * 12 + i);
        ids2[4*i+0] = v.x * 2; ids2[4*i+1] = v.y * 2;
        ids2[4*i+2] = v.z * 2; ids2[4*i+3] = v.w * 2;
    }

    float acc[PPT];
    #pragma unroll
    for (int p = 0; p < PPT; ++p) acc[p] = 0.0f;

    const char* src = (const char*)proj_h;

    for (int c = 0; c < nchunks; ++c) {
        const char* gsrc = src + (size_t)c * CHUNK_BYTES;
        for (int j = wid; j < FILL_UNITS; j += TPB / 64)
            gload_lds16(gsrc + j * 1024 + lane * 16, (char*)lds + j * 1024);
        __syncthreads();                       // drain: fill complete

        int cb2 = c * PAD_BYTE;                // c * CHUNK_NODES * 2
        #pragma unroll
        for (int p = 0; p < PPT; ++p) {
            #pragma unroll
            for (int l = 0; l < 3; ++l) {
                u32 loc = (u32)(ids2[3*p + l] - cb2);      // <0 => huge
                u32 off = loc < (u32)PAD_BYTE ? loc : (u32)PAD_BYTE; // v_min_u32
                const _Float16* q = (const _Float16*)
                    (ldsb + (size_t)l * (PLANE_STRIDE * 2) + off);
                acc[p] += (float)(*q);
            }
        }
        if (c + 1 < nchunks) __syncthreads();  // reads done before next fill
    }

    if (t < n_threads) {
        #pragma unroll
        for (int j = 0; j < PPT / 4; ++j) {
            v4f o;
            #pragma unroll
            for (int q = 0; q < 4; ++q) {
                int p = 4*j + q;
                int cnt = (int)(ids2[3*p] >= 0) + (int)(ids2[3*p+1] >= 0)
                        + (int)(ids2[3*p+2] >= 0);
                float inv = (cnt == 3) ? (1.0f/3.0f) : (cnt == 2 ? 0.5f : 1.0f);
                o[q] = acc[p] * inv;
            }
            __builtin_nontemporal_store(o, ((v4f*)out) + (size_t)t * 4 + j);
        }
    }
}

extern "C" void kernel_launch(void* const* d_in, const int* in_sizes, int n_in,
                              void* d_out, int out_size, void* d_ws, size_t ws_size,
                              hipStream_t stream) {
    const int*   paths = (const int*)d_in[0];     // (N_PATHS, 3) int32
    const float* feat  = (const float*)d_in[1];   // (N_NODES, 128) f32
    const float* W     = (const float*)d_in[2];   // (3, 1, 128) f32
    float*       out   = (float*)d_out;           // (N_PATHS,) f32

    int n_nodes = in_sizes[1] / HIDDEN;           // 100000
    int n_paths = in_sizes[0] / 3;                // 10000000
    u16* proj_h = (u16*)d_ws;                     // nchunks * 156672 B = 612 KB

    int nchunks = (n_nodes + CHUNK_NODES - 1) / CHUNK_NODES;   // 4
    size_t lds_bytes = CHUNK_BYTES;                            // 156672

    (void)hipFuncSetAttribute((const void*)score_kernel,
            hipFuncAttributeMaxDynamicSharedMemorySize, (int)lds_bytes);
    (void)hipGetLastError();   // clear any sticky error pre-capture

    // Kernel 1: 1 wave per node, 4 waves per 256-thread block.
    {
        int blocks = (n_nodes + 3) / 4;
        proj_kernel<<<blocks, 256, 0, stream>>>(feat, W, proj_h,
                                                n_nodes, nchunks);
    }

    // Kernel 2: 16 paths/thread; grid padded to 3 blocks/CU exactly.
    {
        int n_threads = (n_paths + PPT - 1) / PPT;     // 625,000
        int blocks = (n_threads + TPB - 1) / TPB;      // 611
        blocks = ((blocks + 255) / 256) * 256;         // 768 = 3 * 256
        score_kernel<<<blocks, TPB, lds_bytes, stream>>>(paths, proj_h, out,
                                                         n_threads, nchunks);
    }
}

// Round 9
// 288.282 us; speedup vs baseline: 1.1743x; 1.1743x over previous
//
#include <hip/hip_runtime.h>

#define HIDDEN        128
#define TPB           1024
#define PPT           8                    // paths per thread (24 ids + 8 acc: no spill)
#define CHUNK_NODES   25600                // nodes per LDS chunk
#define PLANE_STRIDE  26112                // u16 per plane => chunk bytes % 1024 == 0
#define CHUNK_U16     (3 * PLANE_STRIDE)   // 78336
#define CHUNK_BYTES   (CHUNK_U16 * 2)      // 156672 (153 x 1KB)
#define FILL_UNITS    (CHUNK_BYTES / 1024) // 153 wave DMA units
#define PAD_BYTE      (CHUNK_NODES * 2)    // 51200: zero-slot byte offset in plane

typedef int   v4i __attribute__((ext_vector_type(4)));
typedef float v4f __attribute__((ext_vector_type(4)));
typedef unsigned short u16;
typedef unsigned int   u32;

static __device__ __forceinline__ u16 f32_to_f16_bits(float x) {
    union { _Float16 h; u16 u; } cv;
    cv.h = (_Float16)x;
    return cv.u;
}

// Async global->LDS DMA, 16 B per lane: lane i's 16 B land at lds_base + i*16.
static __device__ __forceinline__ void gload_lds16(const void* gp, void* lp) {
    __builtin_amdgcn_global_load_lds(
        (const __attribute__((address_space(1))) unsigned int*)gp,
        (__attribute__((address_space(3))) unsigned int*)lp,
        16, 0, 0);
}

// Kernel 1: f16 table, chunked layout. Chunk c = 3 planes of PLANE_STRIDE u16;
// plane-local index CHUNK_NODES (byte 51200) is the zero slot that invalid /
// out-of-chunk gathers clamp onto. One wave per node.
__global__ __launch_bounds__(256) void proj_kernel(
    const float* __restrict__ feat,   // (n_nodes, 128)
    const float* __restrict__ W,      // (3, 1, 128)
    u16* __restrict__ proj_h,         // nchunks * CHUNK_U16
    int n_nodes, int nchunks)
{
    int gtid = blockIdx.x * blockDim.x + threadIdx.x;

    // Zero the clamp slots: one per (chunk, plane).
    if (gtid < nchunks * 3) {
        int c = gtid / 3, l = gtid - 3 * c;
        proj_h[(size_t)c * CHUNK_U16 + l * PLANE_STRIDE + CHUNK_NODES] = 0;
    }

    int node = gtid >> 6;
    int lane = threadIdx.x & 63;
    if (node >= n_nodes) return;

    const float2* f2 = (const float2*)(feat + (size_t)node * HIDDEN);
    const float2* w2 = (const float2*)W;

    float2 f   = f2[lane];
    float2 w0  = w2[lane];           // W[0]
    float2 w1  = w2[64 + lane];      // W[1]
    float2 wv2 = w2[128 + lane];     // W[2]

    float s0 = f.x * w0.x  + f.y * w0.y;
    float s1 = f.x * w1.x  + f.y * w1.y;
    float s2 = f.x * wv2.x + f.y * wv2.y;

    #pragma unroll
    for (int off = 32; off > 0; off >>= 1) {
        s0 += __shfl_xor(s0, off, 64);
        s1 += __shfl_xor(s1, off, 64);
        s2 += __shfl_xor(s2, off, 64);
    }

    if (lane == 0) {
        int c     = node / CHUNK_NODES;
        int local = node - c * CHUNK_NODES;
        u16* base = proj_h + (size_t)c * CHUNK_U16 + local;
        base[0]                = f32_to_f16_bits(s0);
        base[PLANE_STRIDE]     = f32_to_f16_bits(s1);
        base[2 * PLANE_STRIDE] = f32_to_f16_bits(s2);
    }
}

// Kernel 2: 8 paths/thread in registers (pre-doubled byte ids); 4 chunk
// passes. Fill = async global_load_lds, zero per-iteration waits (the
// __syncthreads drain is the only wait). Gather addressing is 2 VALU ops:
//   off = min((u32)(id2 - cbase2), PAD_BYTE)  -> clamp lands on zero slot.
// Grid padded to 5 blocks/CU exactly; overrun threads clamp loads, skip
// stores, run every barrier.
__global__ __launch_bounds__(TPB, 4) void score_kernel(
    const int* __restrict__ paths,    // (n_paths, 3) int32
    const u16* __restrict__ proj_h,   // chunked f16 table
    float* __restrict__ out,          // (n_paths,)
    int n_threads, int nchunks)
{
    extern __shared__ u16 lds[];
    const char* ldsb = (const char*)lds;

    int t    = blockIdx.x * TPB + threadIdx.x;
    int tl   = t < n_threads ? t : n_threads - 1;   // clamp: uniform flow
    int wid  = threadIdx.x >> 6;
    int lane = threadIdx.x & 63;

    // 8 paths = 24 ids = 6 int4 loads; ids pre-doubled (byte units, sign kept).
    int ids2[3 * PPT];
    const v4i* p4 = (const v4i*)paths;
    #pragma unroll
    for (int i = 0; i < 6; ++i) {
        v4i v = __builtin_nontemporal_load(p4 + (size_t)tl * 6 + i);
        ids2[4*i+0] = v.x * 2; ids2[4*i+1] = v.y * 2;
        ids2[4*i+2] = v.z * 2; ids2[4*i+3] = v.w * 2;
    }

    float acc[PPT];
    #pragma unroll
    for (int p = 0; p < PPT; ++p) acc[p] = 0.0f;

    const char* src = (const char*)proj_h;

    for (int c = 0; c < nchunks; ++c) {
        const char* gsrc = src + (size_t)c * CHUNK_BYTES;
        for (int j = wid; j < FILL_UNITS; j += TPB / 64)
            gload_lds16(gsrc + j * 1024 + lane * 16, (char*)lds + j * 1024);
        __syncthreads();                       // drain: fill complete

        int cb2 = c * PAD_BYTE;                // c * CHUNK_NODES * 2
        #pragma unroll
        for (int p = 0; p < PPT; ++p) {
            #pragma unroll
            for (int l = 0; l < 3; ++l) {
                u32 loc = (u32)(ids2[3*p + l] - cb2);            // <0 => huge
                u32 off = loc < (u32)PAD_BYTE ? loc : (u32)PAD_BYTE; // v_min_u32
                const _Float16* q = (const _Float16*)
                    (ldsb + (size_t)l * (PLANE_STRIDE * 2) + off);
                acc[p] += (float)(*q);
            }
        }
        if (c + 1 < nchunks) __syncthreads();  // reads done before next fill
    }

    if (t < n_threads) {
        #pragma unroll
        for (int j = 0; j < PPT / 4; ++j) {
            v4f o;
            #pragma unroll
            for (int q = 0; q < 4; ++q) {
                int p = 4*j + q;
                int cnt = (int)(ids2[3*p] >= 0) + (int)(ids2[3*p+1] >= 0)
                        + (int)(ids2[3*p+2] >= 0);
                float inv = (cnt == 3) ? (1.0f/3.0f) : (cnt == 2 ? 0.5f : 1.0f);
                o[q] = acc[p] * inv;
            }
            __builtin_nontemporal_store(o, ((v4f*)out) + (size_t)t * 2 + j);
        }
    }
}

extern "C" void kernel_launch(void* const* d_in, const int* in_sizes, int n_in,
                              void* d_out, int out_size, void* d_ws, size_t ws_size,
                              hipStream_t stream) {
    const int*   paths = (const int*)d_in[0];     // (N_PATHS, 3) int32
    const float* feat  = (const float*)d_in[1];   // (N_NODES, 128) f32
    const float* W     = (const float*)d_in[2];   // (3, 1, 128) f32
    float*       out   = (float*)d_out;           // (N_PATHS,) f32

    int n_nodes = in_sizes[1] / HIDDEN;           // 100000
    int n_paths = in_sizes[0] / 3;                // 10000000
    u16* proj_h = (u16*)d_ws;                     // nchunks * 156672 B = 612 KB

    int nchunks = (n_nodes + CHUNK_NODES - 1) / CHUNK_NODES;   // 4
    size_t lds_bytes = CHUNK_BYTES;                            // 156672

    (void)hipFuncSetAttribute((const void*)score_kernel,
            hipFuncAttributeMaxDynamicSharedMemorySize, (int)lds_bytes);
    (void)hipGetLastError();   // clear any sticky error pre-capture

    // Kernel 1: 1 wave per node, 4 waves per 256-thread block.
    {
        int blocks = (n_nodes + 3) / 4;
        proj_kernel<<<blocks, 256, 0, stream>>>(feat, W, proj_h,
                                                n_nodes, nchunks);
    }

    // Kernel 2: 8 paths/thread; grid padded to 5 blocks/CU exactly.
    {
        int n_threads = (n_paths + PPT - 1) / PPT;     // 1,250,000
        int blocks = (n_threads + TPB - 1) / TPB;      // 1221
        blocks = ((blocks + 255) / 256) * 256;         // 1280 = 5 * 256
        score_kernel<<<blocks, TPB, lds_bytes, stream>>>(paths, proj_h, out,
                                                         n_threads, nchunks);
    }
}